// Round 4
// baseline (658.996 us; speedup 1.0000x reference)
//
#include <hip/hip_runtime.h>

// Problem: N=32, C=1024, B=1024
//   K = Wk@X[n] + Wk0 ; Q = Wq@X[n] + Wq0
//   Y[q,k] = (Q[:,q].K[:,k]) / sqrt(max(|Q_q|^2 |K_k|^2, 1e-12))
//   SM = softmax over q ; Z = X @ SM  -> [N,C,B] fp32
//
// NT GEMM (both operands k-contiguous bf16), 256x256 tile, BK=64, 8 waves,
// 8-phase counted-vmcnt schedule (T2 swizzle + T3/T4 pipeline + T5 setprio).
// THIS ROUND: persistent blocks (grid=256, 1/CU). Each block owns IPB
// CONSECUTIVE work items -> same (n,tileM) A-panel for all its items
// (temporal L2/L3 reuse, no cross-block lockstep = avoids T1's regression).
// The last K-tile's dead issue slots prefetch the NEXT item's tile0 into
// the dead LDS buffer, so the epilogue overlaps the next item's HBM fetch.
// Norms fused into GEMM1 epilogue. Softmax fused into GEMM2/GEMM3:
// |Y|<=1 (cosine) so exp uses fixed shift M=1 (no max pass); the
// normalizer 1/S factors out of Z and is applied in GEMM3's epilogue.
//
// NOTE: __launch_bounds__(512) with NO min-wave clause. (512,2) would cap
// VGPRs at 128 -> acc spills to scratch -> scratch VMEM traffic corrupts
// the hand-counted vmcnt(6) pipeline.

typedef __bf16 bf16x8 __attribute__((ext_vector_type(8)));
typedef float  f32x4  __attribute__((ext_vector_type(4)));

#define LOAD16_LDS(g, l)                                                       \
  __builtin_amdgcn_global_load_lds(                                            \
      (const __attribute__((address_space(1))) void*)(g),                      \
      (__attribute__((address_space(3))) void*)(l), 16, 0, 0)

#define FENCE() asm volatile("" ::: "memory")
#define SBAR()                                                                 \
  do { FENCE(); __builtin_amdgcn_s_barrier(); FENCE(); } while (0)
#define LGKM0()                                                                \
  do { asm volatile("s_waitcnt lgkmcnt(0)" ::: "memory");                      \
       __builtin_amdgcn_sched_barrier(0); } while (0)
#define VMW(n)                                                                 \
  do { asm volatile("s_waitcnt vmcnt(" #n ")" ::: "memory");                   \
       __builtin_amdgcn_sched_barrier(0); } while (0)
#define MFMA16(a, b, c) __builtin_amdgcn_mfma_f32_16x16x32_bf16((a), (b), (c), 0, 0, 0)

// ---------------------------------------------------------------- converts
__global__ __launch_bounds__(256) void convert_w(
    const float* __restrict__ Wk, const float* __restrict__ Wq,
    const float* __restrict__ Wk0, const float* __restrict__ Wq0,
    __bf16* __restrict__ Wb, float* __restrict__ bias2) {
  int i = blockIdx.x * 256 + threadIdx.x;              // 0 .. 2M-1
  if (i < 1048576) Wb[i] = (__bf16)Wk[i];
  else             Wb[i] = (__bf16)Wq[i - 1048576];
  if (i < 1024) bias2[i] = Wk0[i];
  if (i >= 1048576 && i < 1048576 + 1024) bias2[1024 + (i - 1048576)] = Wq0[i - 1048576];
}

__global__ __launch_bounds__(256) void convert_x(
    const float* __restrict__ X, __bf16* __restrict__ Xb, __bf16* __restrict__ Xtb) {
  const int n = blockIdx.z;
  const int c0 = blockIdx.y * 32, b0 = blockIdx.x * 32;
  __shared__ float t[32][33];
  const int tx = threadIdx.x, ty = threadIdx.y;        // 32 x 8
  const float* Xn = X + (size_t)n * 1024 * 1024;
  __bf16* Xbn = Xb + (size_t)n * 1024 * 1024;
  __bf16* Xtn = Xtb + (size_t)n * 1024 * 1024;
#pragma unroll
  for (int i = 0; i < 4; ++i) {
    int c = c0 + ty + i * 8;
    float v = Xn[(size_t)c * 1024 + b0 + tx];
    Xbn[(size_t)c * 1024 + b0 + tx] = (__bf16)v;
    t[ty + i * 8][tx] = v;
  }
  __syncthreads();
#pragma unroll
  for (int i = 0; i < 4; ++i) {
    int b = b0 + ty + i * 8;
    Xtn[(size_t)b * 1024 + c0 + tx] = (__bf16)t[tx][ty + i * 8];
  }
}

// ---------------------------------------------------------------- NT GEMM
// C[m,n'] = sum_k A[m,k] * B[n',k]; A:[M][lda], B:[N][ldb], bf16 rows k-contig.
// 256x256 tile, BK=64, 8 waves (2Mx4N), per-wave C = 128x64.
// LDS per buffer: A[256][64] bf16 (32KB) + B[256][64] (32KB); 2 buffers.
// LDS element (row, colbytes cb) stored at row*128 + (cb ^ ((row&7)<<4));
// staging keeps LDS dest linear and pre-swizzles the GLOBAL source column.
// Chunk c (8KB) of an operand covers rows c*64..c*64+63; thread t supplies
// row c*64 + (t>>3), global col element 8*((t&7)^((t>>3)&7)).
//
// Persistent decode: grid=256; block b owns items b*IPB .. b*IPB+IPB-1.
//   item id: tileN = (id & (2^GXS-1))*256, tileM = ((id>>GXS)&3)*256,
//            n = id >> (GXS+2).  IPB consecutive ids share (n,tileM)
//   (no low-bit carry: baseid*IPB aligned), so gA[] is block-constant and
//   only gB[] advances by 256*ldb per item.
//
// Pipeline (per K-tile, 4 phases; 2 loads = 1 "unit" issued per phase):
//   tile T units: u0=B01, u1=B23, u2=A0A2, u3=A1A3
//   T.p0: read B(all)+A(mi0,1); issue u3(T+1)->nxt
//   T.p1: read A(mi2,3);        issue u0(T+2)->cur.B   (B retired at p0)
//   T.p2: read A(mi4,5);        issue u1(T+2)->cur.B
//   T.p3: read A(mi6,7);        issue u2(T+2)->cur.A02 (retired at p1);
//         vmcnt(6) [NT-2: vmcnt(0); NT-1: no wait]
//   At t=NT-1 (next item exists): p0..p3 issue next item's tile0
//   (u0,u1,u2,u3) into the dead buffer (buf0). After the epilogue:
//   vmcnt(0) (re-anchor: stores/atomics share vmcnt), issue 6 warm loads
//   (tile1 u0,u1,u2 -> buf1), SBAR -> identical steady state to cold start.
//
// EPI 0: bf16 out + bias[col]; fused per-row sum-of-squares -> atomicAdd
// EPI 1: e = exp(v*rsqrt(max(rowS*colS,eps)) - 1) bf16 out; row-sum -> sq0
// EPI 2: f32 out * (1/colS[col])                   (Z, softmax normalizer)
template <int EPI, int IPB, int GXS>
__global__ __launch_bounds__(512) void gemm256(
    const __bf16* __restrict__ A, const __bf16* __restrict__ Bm,
    void* __restrict__ Out, int lda, int ldb, int ldo, int K,
    long long sA, long long sB, long long sO,
    const float* __restrict__ rowS, const float* __restrict__ colS,
    const float* __restrict__ bias,
    float* __restrict__ sq0, float* __restrict__ sq1) {
  extern __shared__ char smem[];

  // ---- persistent decode (block-constant part)
  const int baseid = blockIdx.x * IPB;
  const int tN0   = (baseid & ((1 << GXS) - 1)) * 256;
  const int tileM = ((baseid >> GXS) & 3) * 256;
  const int n     = baseid >> (GXS + 2);

  A += (size_t)n * sA;
  Bm += (size_t)n * sB;

  const int tid = threadIdx.x;                 // 0..511
  const int w = tid >> 6, lane = tid & 63;
  const int wm = w >> 2, wn = w & 3;           // 2 x 4 wave grid
  const int r16 = lane & 15, q16 = lane >> 4;
  const int wb = w * 1024;                     // wave slice inside an 8KB chunk

  // ---- staging source addresses (pre-swizzled global column)
  const int srow = tid >> 3;                                 // 0..63
  const int scol8 = ((tid & 7) ^ (srow & 7)) * 8;            // element offset
  const __bf16* gA[4];
  const __bf16* gB[4];
#pragma unroll
  for (int c = 0; c < 4; ++c) {
    gA[c] = A + (size_t)(tileM + c * 64 + srow) * lda + scol8;
    gB[c] = Bm + (size_t)(tN0 + c * 64 + srow) * ldb + scol8;
  }
  const long long bStep = 256LL * ldb;         // B-panel advance per item

  // ---- fragment-read addressing
  const int sw = (r16 & 7) << 4;
  const int cc0 = (q16 * 16) ^ sw;             // k-half 0, bytes within row
  const int cc1 = cc0 ^ 64;                    // k-half 1
  const int aRow = (wm * 128 + r16) * 128;     // + mi*2048
  const int bRow = (wn * 64 + r16) * 128;      // + ni*2048

  const int NT = K >> 6;                       // 16 K-tiles

#pragma unroll 1
  for (int it = 0; it < IPB; ++it) {
    const int tileN = tN0 + it * 256;
    const bool pre = (it + 1 < IPB);

    f32x4 acc[8][4];
#pragma unroll
    for (int i = 0; i < 8; ++i)
#pragma unroll
      for (int j = 0; j < 4; ++j) acc[i][j] = (f32x4){0.f, 0.f, 0.f, 0.f};

    char* A0 = smem;
    char* B0 = smem + 32768;
    char* A1 = smem + 65536;
    char* B1 = smem + 65536 + 32768;

    if (it == 0) {
      // ---- cold prologue: tile0 u0..u3 (koff 0) + tile1 u0..u2 (koff 64)
      LOAD16_LDS(gB[0], B0 + 0 * 8192 + wb);
      LOAD16_LDS(gB[1], B0 + 1 * 8192 + wb);
      FENCE();
      LOAD16_LDS(gB[2], B0 + 2 * 8192 + wb);
      LOAD16_LDS(gB[3], B0 + 3 * 8192 + wb);
      FENCE();
      LOAD16_LDS(gA[0], A0 + 0 * 8192 + wb);
      LOAD16_LDS(gA[2], A0 + 2 * 8192 + wb);
      FENCE();
      LOAD16_LDS(gA[1], A0 + 1 * 8192 + wb);
      LOAD16_LDS(gA[3], A0 + 3 * 8192 + wb);
      FENCE();
      LOAD16_LDS(gB[0] + 64, B1 + 0 * 8192 + wb);
      LOAD16_LDS(gB[1] + 64, B1 + 1 * 8192 + wb);
      FENCE();
      LOAD16_LDS(gB[2] + 64, B1 + 2 * 8192 + wb);
      LOAD16_LDS(gB[3] + 64, B1 + 3 * 8192 + wb);
      FENCE();
      LOAD16_LDS(gA[0] + 64, A1 + 0 * 8192 + wb);
      LOAD16_LDS(gA[2] + 64, A1 + 2 * 8192 + wb);
      VMW(6);                                  // tile0 fully resident
      SBAR();
    } else {
      // ---- warm prologue: tile0 already resident in buf0 (prefetched at
      // prev item's t=NT-1; drained by the post-epilogue VMW(0)).
      // Issue tile1 u0,u1,u2 -> buf1.
      LOAD16_LDS(gB[0] + 64, B1 + 0 * 8192 + wb);
      LOAD16_LDS(gB[1] + 64, B1 + 1 * 8192 + wb);
      FENCE();
      LOAD16_LDS(gB[2] + 64, B1 + 2 * 8192 + wb);
      LOAD16_LDS(gB[3] + 64, B1 + 3 * 8192 + wb);
      FENCE();
      LOAD16_LDS(gA[0] + 64, A1 + 0 * 8192 + wb);
      LOAD16_LDS(gA[2] + 64, A1 + 2 * 8192 + wb);
      SBAR();
    }

    int kU3 = 64, kU0 = 128, kU1 = 128, kU2 = 128;

    for (int t = 0; t < NT; ++t) {
      char* Ab = smem + (size_t)((t & 1) * 65536);
      char* Bb = Ab + 32768;
      char* An = smem + (size_t)(((t & 1) ^ 1) * 65536);
      char* Bn = An + 32768;

      // B fragments for the whole tile (read once, held in regs)
      bf16x8 bfr[4][2];
#pragma unroll
      for (int ni = 0; ni < 4; ++ni) {
        bfr[ni][0] = *(const bf16x8*)(Bb + bRow + ni * 2048 + cc0);
        bfr[ni][1] = *(const bf16x8*)(Bb + bRow + ni * 2048 + cc1);
      }

#pragma unroll
      for (int p = 0; p < 4; ++p) {
        bf16x8 af[2][2];
#pragma unroll
        for (int j = 0; j < 2; ++j) {
          af[j][0] = *(const bf16x8*)(Ab + aRow + (2 * p + j) * 2048 + cc0);
          af[j][1] = *(const bf16x8*)(Ab + aRow + (2 * p + j) * 2048 + cc1);
        }
        if (p == 0) {
          if (kU3 < K) {                       // u3(t+1) -> next buffer A13
            LOAD16_LDS(gA[1] + kU3, An + 1 * 8192 + wb);
            LOAD16_LDS(gA[3] + kU3, An + 3 * 8192 + wb);
            kU3 += 64;
          } else if (pre && t == NT - 1) {     // nx.u0: next item B01 -> buf0
            LOAD16_LDS(gB[0] + bStep, Bn + 0 * 8192 + wb);
            LOAD16_LDS(gB[1] + bStep, Bn + 1 * 8192 + wb);
          }
        } else if (p == 1) {
          if (kU0 < K) {                       // u0(t+2) -> current B01
            LOAD16_LDS(gB[0] + kU0, Bb + 0 * 8192 + wb);
            LOAD16_LDS(gB[1] + kU0, Bb + 1 * 8192 + wb);
            kU0 += 64;
          } else if (pre && t == NT - 1) {     // nx.u1: next item B23 -> buf0
            LOAD16_LDS(gB[2] + bStep, Bn + 2 * 8192 + wb);
            LOAD16_LDS(gB[3] + bStep, Bn + 3 * 8192 + wb);
          }
        } else if (p == 2) {
          if (kU1 < K) {                       // u1(t+2) -> current B23
            LOAD16_LDS(gB[2] + kU1, Bb + 2 * 8192 + wb);
            LOAD16_LDS(gB[3] + kU1, Bb + 3 * 8192 + wb);
            kU1 += 64;
          } else if (pre && t == NT - 1) {     // nx.u2: next item A02 -> buf0
            LOAD16_LDS(gA[0], An + 0 * 8192 + wb);
            LOAD16_LDS(gA[2], An + 2 * 8192 + wb);
          }
        } else {
          if (kU2 < K) {                       // u2(t+2) -> current A02
            LOAD16_LDS(gA[0] + kU2, Ab + 0 * 8192 + wb);
            LOAD16_LDS(gA[2] + kU2, Ab + 2 * 8192 + wb);
            kU2 += 64;
          } else if (pre && t == NT - 1) {     // nx.u3: next item A13 -> buf0
            LOAD16_LDS(gA[1], An + 1 * 8192 + wb);
            LOAD16_LDS(gA[3], An + 3 * 8192 + wb);
          }
          if (t <= NT - 3)      { VMW(6); }    // next tile resident
          else if (t == NT - 2) { VMW(0); }    // last tile resident
          /* t == NT-1: no wait (prefetch stays in flight over epilogue) */
        }
        SBAR();
        LGKM0();
        __builtin_amdgcn_s_setprio(1);
#pragma unroll
        for (int ni = 0; ni < 4; ++ni) {
#pragma unroll
          for (int j = 0; j < 2; ++j) {
            acc[2 * p + j][ni] = MFMA16(af[j][0], bfr[ni][0], acc[2 * p + j][ni]);
            acc[2 * p + j][ni] = MFMA16(af[j][1], bfr[ni][1], acc[2 * p + j][ni]);
          }
        }
        __builtin_amdgcn_s_setprio(0);
        SBAR();
      }
    }

    // -------------------------------------------------------------- epilogue
    const int rowBase = tileM + wm * 128;
    const int colBase = tileN + wn * 64;
    if (EPI == 0) {
      // bf16 store (+bias) and per-row sum of squares of the ROUNDED values.
      float* sqp = (tileN < 1024) ? sq0 : sq1;
      float bs[4];
#pragma unroll
      for (int ni = 0; ni < 4; ++ni) bs[ni] = bias[colBase + ni * 16 + r16];
#pragma unroll
      for (int mi = 0; mi < 8; ++mi) {
#pragma unroll
        for (int t_ = 0; t_ < 4; ++t_) {
          const int grow = rowBase + mi * 16 + q16 * 4 + t_;
          float ss = 0.f;
#pragma unroll
          for (int ni = 0; ni < 4; ++ni) {
            const int gcol = colBase + ni * 16 + r16;
            const __bf16 bv = (__bf16)(acc[mi][ni][t_] + bs[ni]);
            ((__bf16*)Out)[(size_t)n * sO + (size_t)grow * ldo + gcol] = bv;
            const float f = (float)bv;
            ss += f * f;
          }
          ss += __shfl_xor(ss, 1);
          ss += __shfl_xor(ss, 2);
          ss += __shfl_xor(ss, 4);
          ss += __shfl_xor(ss, 8);
          if (r16 == 0) atomicAdd(&sqp[n * 1024 + grow], ss);
        }
      }
    } else if (EPI == 1) {
      // e = exp(y - 1), y = cosine in [-1,1] -> no max pass needed.
      float cs[4];
#pragma unroll
      for (int ni = 0; ni < 4; ++ni)
        cs[ni] = colS[n * 1024 + colBase + ni * 16 + r16];
#pragma unroll
      for (int mi = 0; mi < 8; ++mi) {
#pragma unroll
        for (int t_ = 0; t_ < 4; ++t_) {
          const int grow = rowBase + mi * 16 + q16 * 4 + t_;
          const float rs = rowS[n * 1024 + grow];
          float ss = 0.f;
#pragma unroll
          for (int ni = 0; ni < 4; ++ni) {
            const int gcol = colBase + ni * 16 + r16;
            const float y = acc[mi][ni][t_] * rsqrtf(fmaxf(rs * cs[ni], 1e-12f));
            const __bf16 e = (__bf16)__expf(y - 1.0f);
            ((__bf16*)Out)[(size_t)n * sO + (size_t)grow * ldo + gcol] = e;
            ss += (float)e;
          }
          ss += __shfl_xor(ss, 1);
          ss += __shfl_xor(ss, 2);
          ss += __shfl_xor(ss, 4);
          ss += __shfl_xor(ss, 8);
          if (r16 == 0) atomicAdd(&sq0[n * 1024 + grow], ss);
        }
      }
    } else {
      float inv[4];
#pragma unroll
      for (int ni = 0; ni < 4; ++ni)
        inv[ni] = 1.0f / colS[n * 1024 + colBase + ni * 16 + r16];
#pragma unroll
      for (int mi = 0; mi < 8; ++mi)
#pragma unroll
        for (int ni = 0; ni < 4; ++ni)
#pragma unroll
          for (int t_ = 0; t_ < 4; ++t_) {
            const int grow = rowBase + mi * 16 + q16 * 4 + t_;
            const int gcol = colBase + ni * 16 + r16;
            ((float*)Out)[(size_t)n * sO + (size_t)grow * ldo + gcol] =
                acc[mi][ni][t_] * inv[ni];
          }
    }

    if (pre) {
      // Re-anchor vmcnt: epilogue stores/atomics share the counter, so the
      // warm path's counted waits would be unsound without a full drain.
      // The 8 prefetched tile0 loads were issued a whole epilogue ago and
      // are effectively resident by now.
      VMW(0);
#pragma unroll
      for (int c = 0; c < 4; ++c) gB[c] += bStep;
    }
  }
}

// ---------------------------------------------------------------- launch
extern "C" void kernel_launch(void* const* d_in, const int* in_sizes, int n_in,
                              void* d_out, int out_size, void* d_ws, size_t ws_size,
                              hipStream_t stream) {
  const float* X   = (const float*)d_in[0];
  const float* Wk  = (const float*)d_in[1];
  const float* Wq  = (const float*)d_in[2];
  const float* Wk0 = (const float*)d_in[3];
  const float* Wq0 = (const float*)d_in[4];

  char* ws = (char*)d_ws;
  const size_t MB = 1ull << 20;
  // layout (peak ~261 MB): ET aliases Xtb (dead after GEMM1)
  __bf16* Xb   = (__bf16*)(ws);              //  64 MB  [N][C][B]
  __bf16* Xtb  = (__bf16*)(ws + 64 * MB);    //  64 MB  [N][B][C]
  __bf16* ET   = (__bf16*)(ws + 64 * MB);    //  64 MB  alias   [N][Bk][Bq]
  __bf16* Wb   = (__bf16*)(ws + 128 * MB);   //   4 MB  [2C][C]
  __bf16* KQT  = (__bf16*)(ws + 132 * MB);   // 128 MB  [N][B][2C]  (K^T | Q^T)
  float*  DK2  = (float*)(ws + 260 * MB);            // 128 KB
  float*  DQ2  = (float*)(ws + 260 * MB + 128 * 1024);
  float*  S    = (float*)(ws + 260 * MB + 256 * 1024); // ET row sums
  float*  bias2= (float*)(ws + 260 * MB + 384 * 1024);

  const long long M1 = 1024LL * 1024LL;

  // Opt-in for 128 KiB dynamic LDS (cheap host-side calls; unconditional).
  hipFuncSetAttribute(reinterpret_cast<const void*>(&gemm256<0, 4, 3>),
                      hipFuncAttributeMaxDynamicSharedMemorySize, 131072);
  hipFuncSetAttribute(reinterpret_cast<const void*>(&gemm256<1, 2, 2>),
                      hipFuncAttributeMaxDynamicSharedMemorySize, 131072);
  hipFuncSetAttribute(reinterpret_cast<const void*>(&gemm256<2, 2, 2>),
                      hipFuncAttributeMaxDynamicSharedMemorySize, 131072);

  hipMemsetAsync(DK2, 0, 3 * 128 * 1024, stream);  // zero DK2, DQ2, S

  convert_w<<<8192, 256, 0, stream>>>(Wk, Wq, Wk0, Wq0, Wb, bias2);
  convert_x<<<dim3(32, 32, 32), dim3(32, 8), 0, stream>>>(X, Xb, Xtb);

  // GEMM1: KQT[n][b][c2] = sum_d Xtb[n][b][d] * Wb[c2][d] + bias2[c2]
  //        fused: DK2[n][b] = sum K^2, DQ2[n][b] = sum Q^2
  //        1024 items, 256 persistent blocks x 4 items
  gemm256<0, 4, 3><<<dim3(256), 512, 131072, stream>>>(
      Xtb, Wb, KQT, 1024, 1024, 2048, 1024, M1, 0LL, 2 * M1,
      nullptr, nullptr, bias2, DK2, DQ2);

  // GEMM2: ET[n][k][q] = exp(cos(K_k,Q_q) - 1)  (bf16), S[n][k] = row sums
  //        512 items, 256 blocks x 2 items
  gemm256<1, 2, 2><<<dim3(256), 512, 131072, stream>>>(
      KQT, KQT + 1024, ET, 2048, 2048, 1024, 1024, 2 * M1, 2 * M1, M1,
      DK2, DQ2, nullptr, S, nullptr);

  // GEMM3: Z[n][c][j] = (sum_q Xb[n][c][q] * ET[n][j][q]) / S[n][j]
  gemm256<2, 2, 2><<<dim3(256), 512, 131072, stream>>>(
      Xb, ET, (float*)d_out, 1024, 1024, 1024, 1024, M1, M1, M1,
      nullptr, S, nullptr, nullptr, nullptr);
}

// Round 6
// 643.852 us; speedup vs baseline: 1.0235x; 1.0235x over previous
//
#include <hip/hip_runtime.h>

// Problem: N=32, C=1024, B=1024
//   K = Wk@X[n] + Wk0 ; Q = Wq@X[n] + Wq0
//   Y[q,k] = (Q[:,q].K[:,k]) / sqrt(max(|Q_q|^2 |K_k|^2, 1e-12))
//   SM = softmax over q ; Z = X @ SM  -> [N,C,B] fp32
//
// NT GEMM (both operands k-contiguous bf16), 256x256 tile, BK=64, 8 waves,
// 8-phase counted-vmcnt schedule (T2 swizzle + T3/T4 pipeline + T5 setprio).
// THIS ROUND (on the proven R2 structure and proven VMW(6) schedule):
//  (1) anti-camping pads: Xtb/ET/Xb ld=1032 (2064B = 129*16B), KQT ld=2056
//      (4112B = 257*16B) -> staged 64-row chunks spread across channels.
//  (2) footprint discipline: peak was the R5 failure suspect. Xb is now
//      created AFTER GEMM2 (aliases dead KQT region) -> peak 197.5 MiB,
//      well under the proven 273.0 MB bound. Extra convert ~+20us.
// Norms fused into GEMM1 epilogue. Softmax fused into GEMM2/GEMM3:
// |Y|<=1 (cosine) so exp uses fixed shift M=1 (no max pass); the
// normalizer 1/S factors out of Z and is applied in GEMM3's epilogue.
//
// NOTE: __launch_bounds__(512) with NO min-wave clause. (512,2) would cap
// VGPRs at 128 -> acc spills to scratch -> scratch VMEM traffic corrupts
// the hand-counted vmcnt pipeline.

typedef __bf16 bf16x8 __attribute__((ext_vector_type(8)));
typedef float  f32x4  __attribute__((ext_vector_type(4)));

#define LOAD16_LDS(g, l)                                                       \
  __builtin_amdgcn_global_load_lds(                                            \
      (const __attribute__((address_space(1))) void*)(g),                      \
      (__attribute__((address_space(3))) void*)(l), 16, 0, 0)

#define FENCE() asm volatile("" ::: "memory")
#define SBAR()                                                                 \
  do { FENCE(); __builtin_amdgcn_s_barrier(); FENCE(); } while (0)
#define LGKM0()                                                                \
  do { asm volatile("s_waitcnt lgkmcnt(0)" ::: "memory");                      \
       __builtin_amdgcn_sched_barrier(0); } while (0)
#define VMW(n)                                                                 \
  do { asm volatile("s_waitcnt vmcnt(" #n ")" ::: "memory");                   \
       __builtin_amdgcn_sched_barrier(0); } while (0)
#define MFMA16(a, b, c) __builtin_amdgcn_mfma_f32_16x16x32_bf16((a), (b), (c), 0, 0, 0)

// padded leading dims (element counts); multiples of 8 (16B-aligned rows),
// odd multiples of 16B -> maximal channel/bank spread for stride-ld walks.
#define LDX 1032   // Xtb, ET, Xb rows
#define LDK 2056   // KQT rows
#define SX  (1024LL * LDX)   // per-n stride, Xtb/ET/Xb
#define SK  (1024LL * LDK)   // per-n stride, KQT

// ---------------------------------------------------------------- converts
__global__ __launch_bounds__(256) void convert_w(
    const float* __restrict__ Wk, const float* __restrict__ Wq,
    const float* __restrict__ Wk0, const float* __restrict__ Wq0,
    __bf16* __restrict__ Wb, float* __restrict__ bias2) {
  int i = blockIdx.x * 256 + threadIdx.x;              // 0 .. 2M-1
  if (i < 1048576) Wb[i] = (__bf16)Wk[i];
  else             Wb[i] = (__bf16)Wq[i - 1048576];
  if (i < 1024) bias2[i] = Wk0[i];
  if (i >= 1048576 && i < 1048576 + 1024) bias2[1024 + (i - 1048576)] = Wq0[i - 1048576];
}

// transpose-only now: Xtb[n][b][c] = X[n][c][b]  (bf16, padded ld)
__global__ __launch_bounds__(256) void convert_x(
    const float* __restrict__ X, __bf16* __restrict__ Xtb) {
  const int n = blockIdx.z;
  const int c0 = blockIdx.y * 32, b0 = blockIdx.x * 32;
  __shared__ float t[32][33];
  const int tx = threadIdx.x, ty = threadIdx.y;        // 32 x 8
  const float* Xn = X + (size_t)n * 1024 * 1024;
  __bf16* Xtn = Xtb + (size_t)n * SX;
#pragma unroll
  for (int i = 0; i < 4; ++i) {
    int c = c0 + ty + i * 8;
    t[ty + i * 8][tx] = Xn[(size_t)c * 1024 + b0 + tx];
  }
  __syncthreads();
#pragma unroll
  for (int i = 0; i < 4; ++i) {
    int b = b0 + ty + i * 8;
    Xtn[(size_t)b * LDX + c0 + tx] = (__bf16)t[tx][ty + i * 8];
  }
}

// Xb[n][c][b] = X[n][c][b] (bf16, padded ld). Runs AFTER GEMM2 (Xb aliases
// the dead KQT region). One block per (c,n) row; 256 thr x 4 f32.
__global__ __launch_bounds__(256) void convert_xb(
    const float* __restrict__ X, __bf16* __restrict__ Xb) {
  const int c = blockIdx.x, n = blockIdx.y;
  const float* src = X + ((size_t)n * 1024 + c) * 1024 + threadIdx.x * 4;
  __bf16* dst = Xb + (size_t)n * SX + (size_t)c * LDX + threadIdx.x * 4;
  float4 v = *(const float4*)src;
  __bf16 o[4] = {(__bf16)v.x, (__bf16)v.y, (__bf16)v.z, (__bf16)v.w};
  *(ushort4*)dst = *(const ushort4*)o;
}

// ---------------------------------------------------------------- NT GEMM
// C[m,n'] = sum_k A[m,k] * B[n',k]; A:[M][lda], B:[N][ldb], bf16 rows k-contig.
// 256x256 tile, BK=64, 8 waves (2Mx4N), per-wave C = 128x64.
// LDS per buffer: A[256][64] bf16 (32KB) + B[256][64] (32KB); 2 buffers.
// LDS element (row, colbytes cb) stored at row*128 + (cb ^ ((row&7)<<4));
// staging keeps LDS dest linear and pre-swizzles the GLOBAL source column.
// Chunk c (8KB) of an operand covers rows c*64..c*64+63; thread t supplies
// row c*64 + (t>>3), global col element 8*((t&7)^((t>>3)&7)).
//
// Pipeline (per K-tile, 4 phases; 2 loads = 1 "unit" issued per phase):
//   tile T units: u0=B01, u1=B23, u2=A0A2, u3=A1A3
//   T.p0: read B(all)+A(mi0,1); issue u3(T+1)->nxt
//   T.p1: read A(mi2,3);        issue u0(T+2)->cur.B   (B retired at p0)
//   T.p2: read A(mi4,5);        issue u1(T+2)->cur.B
//   T.p3: read A(mi6,7);        issue u2(T+2)->cur.A02 (retired at p1);
//         vmcnt(6) [last 2 boundaries: vmcnt(0)]
//   each phase: barrier; lgkmcnt(0); setprio(1); 16 MFMA; setprio(0); barrier
//
// EPI 0: bf16 out + bias[col]; fused per-row sum-of-squares -> atomicAdd
// EPI 1: e = exp(v*rsqrt(max(rowS*colS,eps)) - 1) bf16 out; row-sum -> sq0
// EPI 2: f32 out * (1/colS[col])                   (Z, softmax normalizer)
template <int EPI>
__global__ __launch_bounds__(512) void gemm256(
    const __bf16* __restrict__ A, const __bf16* __restrict__ Bm,
    void* __restrict__ Out, int lda, int ldb, int ldo, int K,
    long long sA, long long sB, long long sO,
    const float* __restrict__ rowS, const float* __restrict__ colS,
    const float* __restrict__ bias,
    float* __restrict__ sq0, float* __restrict__ sq1) {
  extern __shared__ char smem[];
  const int n = blockIdx.z;
  A += (size_t)n * sA;
  Bm += (size_t)n * sB;
  const int tileM = blockIdx.y * 256, tileN = blockIdx.x * 256;

  const int tid = threadIdx.x;                 // 0..511
  const int w = tid >> 6, lane = tid & 63;
  const int wm = w >> 2, wn = w & 3;           // 2 x 4 wave grid
  const int r16 = lane & 15, q16 = lane >> 4;
  const int wb = w * 1024;                     // wave slice inside an 8KB chunk

  // ---- staging source addresses (pre-swizzled global column)
  const int srow = tid >> 3;                                 // 0..63
  const int scol8 = ((tid & 7) ^ (srow & 7)) * 8;            // element offset
  const __bf16* gA[4];
  const __bf16* gB[4];
#pragma unroll
  for (int c = 0; c < 4; ++c) {
    gA[c] = A + (size_t)(tileM + c * 64 + srow) * lda + scol8;
    gB[c] = Bm + (size_t)(tileN + c * 64 + srow) * ldb + scol8;
  }

  // ---- fragment-read addressing
  const int sw = (r16 & 7) << 4;
  const int cc0 = (q16 * 16) ^ sw;             // k-half 0, bytes within row
  const int cc1 = cc0 ^ 64;                    // k-half 1
  const int aRow = (wm * 128 + r16) * 128;     // + mi*2048
  const int bRow = (wn * 64 + r16) * 128;      // + ni*2048

  f32x4 acc[8][4];
#pragma unroll
  for (int i = 0; i < 8; ++i)
#pragma unroll
    for (int j = 0; j < 4; ++j) acc[i][j] = (f32x4){0.f, 0.f, 0.f, 0.f};

  const int NT = K >> 6;                       // 16 K-tiles

  // ---- prologue: tile0 u0..u3 (koff 0) + tile1 u0..u2 (koff 64)
  {
    char* A0 = smem;
    char* B0 = smem + 32768;
    char* A1 = smem + 65536;
    char* B1 = smem + 65536 + 32768;
    LOAD16_LDS(gB[0], B0 + 0 * 8192 + wb);
    LOAD16_LDS(gB[1], B0 + 1 * 8192 + wb);
    FENCE();
    LOAD16_LDS(gB[2], B0 + 2 * 8192 + wb);
    LOAD16_LDS(gB[3], B0 + 3 * 8192 + wb);
    FENCE();
    LOAD16_LDS(gA[0], A0 + 0 * 8192 + wb);
    LOAD16_LDS(gA[2], A0 + 2 * 8192 + wb);
    FENCE();
    LOAD16_LDS(gA[1], A0 + 1 * 8192 + wb);
    LOAD16_LDS(gA[3], A0 + 3 * 8192 + wb);
    FENCE();
    LOAD16_LDS(gB[0] + 64, B1 + 0 * 8192 + wb);
    LOAD16_LDS(gB[1] + 64, B1 + 1 * 8192 + wb);
    FENCE();
    LOAD16_LDS(gB[2] + 64, B1 + 2 * 8192 + wb);
    LOAD16_LDS(gB[3] + 64, B1 + 3 * 8192 + wb);
    FENCE();
    LOAD16_LDS(gA[0] + 64, A1 + 0 * 8192 + wb);
    LOAD16_LDS(gA[2] + 64, A1 + 2 * 8192 + wb);
    VMW(6);                                    // tile0 fully resident
    SBAR();
  }

  int kU3 = 64, kU0 = 128, kU1 = 128, kU2 = 128;

  for (int t = 0; t < NT; ++t) {
    char* Ab = smem + (size_t)((t & 1) * 65536);
    char* Bb = Ab + 32768;
    char* An = smem + (size_t)(((t & 1) ^ 1) * 65536);

    // B fragments for the whole tile (read once, held in regs)
    bf16x8 bfr[4][2];
#pragma unroll
    for (int ni = 0; ni < 4; ++ni) {
      bfr[ni][0] = *(const bf16x8*)(Bb + bRow + ni * 2048 + cc0);
      bfr[ni][1] = *(const bf16x8*)(Bb + bRow + ni * 2048 + cc1);
    }

#pragma unroll
    for (int p = 0; p < 4; ++p) {
      bf16x8 af[2][2];
#pragma unroll
      for (int j = 0; j < 2; ++j) {
        af[j][0] = *(const bf16x8*)(Ab + aRow + (2 * p + j) * 2048 + cc0);
        af[j][1] = *(const bf16x8*)(Ab + aRow + (2 * p + j) * 2048 + cc1);
      }
      if (p == 0) {
        if (kU3 < K) {
          LOAD16_LDS(gA[1] + kU3, An + 1 * 8192 + wb);
          LOAD16_LDS(gA[3] + kU3, An + 3 * 8192 + wb);
          kU3 += 64;
        }
      } else if (p == 1) {
        if (kU0 < K) {
          LOAD16_LDS(gB[0] + kU0, Bb + 0 * 8192 + wb);
          LOAD16_LDS(gB[1] + kU0, Bb + 1 * 8192 + wb);
          kU0 += 64;
        }
      } else if (p == 2) {
        if (kU1 < K) {
          LOAD16_LDS(gB[2] + kU1, Bb + 2 * 8192 + wb);
          LOAD16_LDS(gB[3] + kU1, Bb + 3 * 8192 + wb);
          kU1 += 64;
        }
      } else {
        if (kU2 < K) {
          LOAD16_LDS(gA[0] + kU2, Ab + 0 * 8192 + wb);
          LOAD16_LDS(gA[2] + kU2, Ab + 2 * 8192 + wb);
          kU2 += 64;
        }
        if (t < NT - 2) { VMW(6); } else { VMW(0); }  // next tile resident
      }
      SBAR();
      LGKM0();
      __builtin_amdgcn_s_setprio(1);
#pragma unroll
      for (int ni = 0; ni < 4; ++ni) {
#pragma unroll
        for (int j = 0; j < 2; ++j) {
          acc[2 * p + j][ni] = MFMA16(af[j][0], bfr[ni][0], acc[2 * p + j][ni]);
          acc[2 * p + j][ni] = MFMA16(af[j][1], bfr[ni][1], acc[2 * p + j][ni]);
        }
      }
      __builtin_amdgcn_s_setprio(0);
      SBAR();
    }
  }

  // ---------------------------------------------------------------- epilogue
  const int rowBase = tileM + wm * 128;
  const int colBase = tileN + wn * 64;
  if (EPI == 0) {
    // bf16 store (+bias) and per-row sum of squares of the ROUNDED values.
    float* sqp = (tileN < 1024) ? sq0 : sq1;
    float bs[4];
#pragma unroll
    for (int ni = 0; ni < 4; ++ni) bs[ni] = bias[colBase + ni * 16 + r16];
#pragma unroll
    for (int mi = 0; mi < 8; ++mi) {
#pragma unroll
      for (int t_ = 0; t_ < 4; ++t_) {
        const int grow = rowBase + mi * 16 + q16 * 4 + t_;
        float ss = 0.f;
#pragma unroll
        for (int ni = 0; ni < 4; ++ni) {
          const int gcol = colBase + ni * 16 + r16;
          const __bf16 bv = (__bf16)(acc[mi][ni][t_] + bs[ni]);
          ((__bf16*)Out)[(size_t)n * sO + (size_t)grow * ldo + gcol] = bv;
          const float f = (float)bv;
          ss += f * f;
        }
        ss += __shfl_xor(ss, 1);
        ss += __shfl_xor(ss, 2);
        ss += __shfl_xor(ss, 4);
        ss += __shfl_xor(ss, 8);
        if (r16 == 0) atomicAdd(&sqp[n * 1024 + grow], ss);
      }
    }
  } else if (EPI == 1) {
    // e = exp(y - 1), y = cosine in [-1,1] -> no max pass needed.
    float cs[4];
#pragma unroll
    for (int ni = 0; ni < 4; ++ni)
      cs[ni] = colS[n * 1024 + colBase + ni * 16 + r16];
#pragma unroll
    for (int mi = 0; mi < 8; ++mi) {
#pragma unroll
      for (int t_ = 0; t_ < 4; ++t_) {
        const int grow = rowBase + mi * 16 + q16 * 4 + t_;
        const float rs = rowS[n * 1024 + grow];
        float ss = 0.f;
#pragma unroll
        for (int ni = 0; ni < 4; ++ni) {
          const int gcol = colBase + ni * 16 + r16;
          const float y = acc[mi][ni][t_] * rsqrtf(fmaxf(rs * cs[ni], 1e-12f));
          const __bf16 e = (__bf16)__expf(y - 1.0f);
          ((__bf16*)Out)[(size_t)n * sO + (size_t)grow * ldo + gcol] = e;
          ss += (float)e;
        }
        ss += __shfl_xor(ss, 1);
        ss += __shfl_xor(ss, 2);
        ss += __shfl_xor(ss, 4);
        ss += __shfl_xor(ss, 8);
        if (r16 == 0) atomicAdd(&sq0[n * 1024 + grow], ss);
      }
    }
  } else {
    float inv[4];
#pragma unroll
    for (int ni = 0; ni < 4; ++ni)
      inv[ni] = 1.0f / colS[n * 1024 + colBase + ni * 16 + r16];
#pragma unroll
    for (int mi = 0; mi < 8; ++mi)
#pragma unroll
      for (int ni = 0; ni < 4; ++ni)
#pragma unroll
        for (int t_ = 0; t_ < 4; ++t_) {
          const int grow = rowBase + mi * 16 + q16 * 4 + t_;
          const int gcol = colBase + ni * 16 + r16;
          ((float*)Out)[(size_t)n * sO + (size_t)grow * ldo + gcol] =
              acc[mi][ni][t_] * inv[ni];
        }
  }
}

// ---------------------------------------------------------------- launch
extern "C" void kernel_launch(void* const* d_in, const int* in_sizes, int n_in,
                              void* d_out, int out_size, void* d_ws, size_t ws_size,
                              hipStream_t stream) {
  const float* X   = (const float*)d_in[0];
  const float* Wk  = (const float*)d_in[1];
  const float* Wq  = (const float*)d_in[2];
  const float* Wk0 = (const float*)d_in[3];
  const float* Wq0 = (const float*)d_in[4];

  char* ws = (char*)d_ws;
  // layout, peak 207,093,760 B = 197.5 MiB (well under proven 273.0 MB):
  //   DK2   @ 0          (131072)
  //   DQ2   @ 131072     (131072)
  //   S     @ 262144     (131072)
  //   bias2 @ 393216     (8192)
  //   Xtb/ET@ 524288     (67,633,152)  [N][B][LDX]  (ET aliases, dead after G1)
  //   Wb    @ 68,157,440 (4,194,304)   [2C][C]
  //   KQT   @ 72,351,744 (134,742,016) [N][B][LDK]  (K^T | Q^T)
  //   Xb    @ 72,351,744 (67,633,152)  aliases KQT; written AFTER GEMM2
  float*  DK2  = (float*)(ws);
  float*  DQ2  = (float*)(ws + 131072);
  float*  S    = (float*)(ws + 262144);
  float*  bias2= (float*)(ws + 393216);
  __bf16* Xtb  = (__bf16*)(ws + 524288);
  __bf16* ET   = (__bf16*)(ws + 524288);        // alias (Xtb dead after G1)
  __bf16* Wb   = (__bf16*)(ws + 68157440ull);
  __bf16* KQT  = (__bf16*)(ws + 72351744ull);
  __bf16* Xb   = (__bf16*)(ws + 72351744ull);   // alias (KQT dead after G2)

  // Opt-in for 128 KiB dynamic LDS (cheap host-side calls; unconditional).
  hipFuncSetAttribute(reinterpret_cast<const void*>(&gemm256<0>),
                      hipFuncAttributeMaxDynamicSharedMemorySize, 131072);
  hipFuncSetAttribute(reinterpret_cast<const void*>(&gemm256<1>),
                      hipFuncAttributeMaxDynamicSharedMemorySize, 131072);
  hipFuncSetAttribute(reinterpret_cast<const void*>(&gemm256<2>),
                      hipFuncAttributeMaxDynamicSharedMemorySize, 131072);

  hipMemsetAsync(DK2, 0, 3 * 131072, stream);  // zero DK2, DQ2, S

  convert_w<<<8192, 256, 0, stream>>>(Wk, Wq, Wk0, Wq0, Wb, bias2);
  convert_x<<<dim3(32, 32, 32), dim3(32, 8), 0, stream>>>(X, Xtb);

  // GEMM1: KQT[n][b][c2] = sum_d Xtb[n][b][d] * Wb[c2][d] + bias2[c2]
  //        fused: DK2[n][b] = sum K^2, DQ2[n][b] = sum Q^2
  gemm256<0><<<dim3(8, 4, 32), 512, 131072, stream>>>(
      Xtb, Wb, KQT, LDX, 1024, LDK, 1024, SX, 0LL, SK,
      nullptr, nullptr, bias2, DK2, DQ2);

  // GEMM2: ET[n][k][q] = exp(cos(K_k,Q_q) - 1)  (bf16), S[n][k] = row sums
  gemm256<1><<<dim3(4, 4, 32), 512, 131072, stream>>>(
      KQT, KQT + 1024, ET, LDK, LDK, LDX, 1024, SK, SK, SX,
      DK2, DQ2, nullptr, S, nullptr);

  // Xb (padded) into the now-dead KQT region.
  convert_xb<<<dim3(1024, 32), 256, 0, stream>>>(X, Xb);

  // GEMM3: Z[n][c][j] = (sum_q Xb[n][c][q] * ET[n][j][q]) / S[n][j]
  gemm256<2><<<dim3(4, 4, 32), 512, 131072, stream>>>(
      Xb, ET, (float*)d_out, LDX, LDX, 1024, 1024, SX, SX, 1024LL * 1024LL,
      nullptr, S, nullptr, nullptr, nullptr);
}

// Round 7
// 591.815 us; speedup vs baseline: 1.1135x; 1.0879x over previous
//
#include <hip/hip_runtime.h>

// Problem: N=32, C=1024, B=1024
//   K = Wk@X[n] + Wk0 ; Q = Wq@X[n] + Wq0
//   Y[q,k] = (Q[:,q].K[:,k]) / sqrt(max(|Q_q|^2 |K_k|^2, 1e-12))
//   SM = softmax over q ; Z = X @ SM  -> [N,C,B] fp32
//
// NT GEMM (both operands k-contiguous bf16), 256x256 tile, BK=64, 8 waves,
// 8-phase counted-vmcnt schedule (T2 swizzle + T3/T4 pipeline + T5 setprio).
// THIS ROUND: byte-identical to the best R2 kernel EXCEPT a deeper counted
// vmcnt: u3's retirement moves from t.p3 (VMW(6)) to (t+1).p1 (VMW(10)),
// extending its load cover from 3 to 5 phases (14 loads in flight).
// Single-variable experiment for the exposed-latency theory on GEMM2/3
// (both operands L3-resident; their blocks run 2x slower than GEMM1's).
// Norms fused into GEMM1 epilogue. Softmax fused into GEMM2/GEMM3:
// |Y|<=1 (cosine) so exp uses fixed shift M=1 (no max pass); the
// normalizer 1/S factors out of Z and is applied in GEMM3's epilogue.
//
// NOTE: __launch_bounds__(512) with NO min-wave clause. (512,2) would cap
// VGPRs at 128 -> acc spills to scratch -> scratch VMEM traffic corrupts
// the hand-counted vmcnt pipeline.

typedef __bf16 bf16x8 __attribute__((ext_vector_type(8)));
typedef float  f32x4  __attribute__((ext_vector_type(4)));

#define LOAD16_LDS(g, l)                                                       \
  __builtin_amdgcn_global_load_lds(                                            \
      (const __attribute__((address_space(1))) void*)(g),                      \
      (__attribute__((address_space(3))) void*)(l), 16, 0, 0)

#define FENCE() asm volatile("" ::: "memory")
#define SBAR()                                                                 \
  do { FENCE(); __builtin_amdgcn_s_barrier(); FENCE(); } while (0)
#define LGKM0()                                                                \
  do { asm volatile("s_waitcnt lgkmcnt(0)" ::: "memory");                      \
       __builtin_amdgcn_sched_barrier(0); } while (0)
#define VMW(n)                                                                 \
  do { asm volatile("s_waitcnt vmcnt(" #n ")" ::: "memory");                   \
       __builtin_amdgcn_sched_barrier(0); } while (0)
#define MFMA16(a, b, c) __builtin_amdgcn_mfma_f32_16x16x32_bf16((a), (b), (c), 0, 0, 0)

// ---------------------------------------------------------------- converts
__global__ __launch_bounds__(256) void convert_w(
    const float* __restrict__ Wk, const float* __restrict__ Wq,
    const float* __restrict__ Wk0, const float* __restrict__ Wq0,
    __bf16* __restrict__ Wb, float* __restrict__ bias2) {
  int i = blockIdx.x * 256 + threadIdx.x;              // 0 .. 2M-1
  if (i < 1048576) Wb[i] = (__bf16)Wk[i];
  else             Wb[i] = (__bf16)Wq[i - 1048576];
  if (i < 1024) bias2[i] = Wk0[i];
  if (i >= 1048576 && i < 1048576 + 1024) bias2[1024 + (i - 1048576)] = Wq0[i - 1048576];
}

__global__ __launch_bounds__(256) void convert_x(
    const float* __restrict__ X, __bf16* __restrict__ Xb, __bf16* __restrict__ Xtb) {
  const int n = blockIdx.z;
  const int c0 = blockIdx.y * 32, b0 = blockIdx.x * 32;
  __shared__ float t[32][33];
  const int tx = threadIdx.x, ty = threadIdx.y;        // 32 x 8
  const float* Xn = X + (size_t)n * 1024 * 1024;
  __bf16* Xbn = Xb + (size_t)n * 1024 * 1024;
  __bf16* Xtn = Xtb + (size_t)n * 1024 * 1024;
#pragma unroll
  for (int i = 0; i < 4; ++i) {
    int c = c0 + ty + i * 8;
    float v = Xn[(size_t)c * 1024 + b0 + tx];
    Xbn[(size_t)c * 1024 + b0 + tx] = (__bf16)v;
    t[ty + i * 8][tx] = v;
  }
  __syncthreads();
#pragma unroll
  for (int i = 0; i < 4; ++i) {
    int b = b0 + ty + i * 8;
    Xtn[(size_t)b * 1024 + c0 + tx] = (__bf16)t[tx][ty + i * 8];
  }
}

// ---------------------------------------------------------------- NT GEMM
// C[m,n'] = sum_k A[m,k] * B[n',k]; A:[M][lda], B:[N][ldb], bf16 rows k-contig.
// 256x256 tile, BK=64, 8 waves (2Mx4N), per-wave C = 128x64.
// LDS per buffer: A[256][64] bf16 (32KB) + B[256][64] (32KB); 2 buffers.
// LDS element (row, colbytes cb) stored at row*128 + (cb ^ ((row&7)<<4));
// staging keeps LDS dest linear and pre-swizzles the GLOBAL source column.
// Chunk c (8KB) of an operand covers rows c*64..c*64+63; thread t supplies
// row c*64 + (t>>3), global col element 8*((t&7)^((t>>3)&7)).
//
// Pipeline (per K-tile, 4 phases; 2 loads = 1 "unit" issued per phase):
//   tile T units: u0=B01, u1=B23, u2=A0A2, u3=A1A3
//   T.p0: read B(all)+A(mi0,1); issue u3(T+1)->nxt
//   T.p1: read A(mi2,3);        issue u0(T+2)->cur.B
//         VMW: 10 (t<=NT-3) / 8 (t==NT-2) / 0 (t==NT-1)  [retires u3(T)]
//   T.p2: read A(mi4,5);        issue u1(T+2)->cur.B
//   T.p3: read A(mi6,7);        issue u2(T+2)->cur.A02
//         VMW: 8 (t<=NT-3) / 2 (t==NT-2) / none (t==NT-1) [retires u2(T+1)]
//   each phase: barrier; lgkmcnt(0); setprio(1); 16 MFMA; setprio(0); barrier
//   Audit: u0,u1,u2(T+1) retired by T.p3 wait (before T+1's bfr + chunk0/2
//   af reads); u3(T+1) [chunks 1,3] retired by (T+1).p1 wait (before p2's
//   chunk1/3 af reads). Write-after-read: every issue target's last LDS
//   read completed >=1 barrier earlier (same proof as R2). Tail counts
//   re-derived with skipped issues; t=0/1 waits are no-ops or exact.
//
// EPI 0: bf16 out + bias[col]; fused per-row sum-of-squares -> atomicAdd
// EPI 1: e = exp(v*rsqrt(max(rowS*colS,eps)) - 1) bf16 out; row-sum -> sq0
// EPI 2: f32 out * (1/colS[col])                   (Z, softmax normalizer)
template <int EPI>
__global__ __launch_bounds__(512) void gemm256(
    const __bf16* __restrict__ A, const __bf16* __restrict__ Bm,
    void* __restrict__ Out, int lda, int ldb, int ldo, int K,
    long long sA, long long sB, long long sO,
    const float* __restrict__ rowS, const float* __restrict__ colS,
    const float* __restrict__ bias,
    float* __restrict__ sq0, float* __restrict__ sq1) {
  extern __shared__ char smem[];
  const int n = blockIdx.z;
  A += (size_t)n * sA;
  Bm += (size_t)n * sB;
  const int tileM = blockIdx.y * 256, tileN = blockIdx.x * 256;

  const int tid = threadIdx.x;                 // 0..511
  const int w = tid >> 6, lane = tid & 63;
  const int wm = w >> 2, wn = w & 3;           // 2 x 4 wave grid
  const int r16 = lane & 15, q16 = lane >> 4;
  const int wb = w * 1024;                     // wave slice inside an 8KB chunk

  // ---- staging source addresses (pre-swizzled global column)
  const int srow = tid >> 3;                                 // 0..63
  const int scol8 = ((tid & 7) ^ (srow & 7)) * 8;            // element offset
  const __bf16* gA[4];
  const __bf16* gB[4];
#pragma unroll
  for (int c = 0; c < 4; ++c) {
    gA[c] = A + (size_t)(tileM + c * 64 + srow) * lda + scol8;
    gB[c] = Bm + (size_t)(tileN + c * 64 + srow) * ldb + scol8;
  }

  // ---- fragment-read addressing
  const int sw = (r16 & 7) << 4;
  const int cc0 = (q16 * 16) ^ sw;             // k-half 0, bytes within row
  const int cc1 = cc0 ^ 64;                    // k-half 1
  const int aRow = (wm * 128 + r16) * 128;     // + mi*2048
  const int bRow = (wn * 64 + r16) * 128;      // + ni*2048

  f32x4 acc[8][4];
#pragma unroll
  for (int i = 0; i < 8; ++i)
#pragma unroll
    for (int j = 0; j < 4; ++j) acc[i][j] = (f32x4){0.f, 0.f, 0.f, 0.f};

  const int NT = K >> 6;                       // 16 K-tiles

  // ---- prologue: tile0 u0..u3 (koff 0) + tile1 u0..u2 (koff 64)
  {
    char* A0 = smem;
    char* B0 = smem + 32768;
    char* A1 = smem + 65536;
    char* B1 = smem + 65536 + 32768;
    LOAD16_LDS(gB[0], B0 + 0 * 8192 + wb);
    LOAD16_LDS(gB[1], B0 + 1 * 8192 + wb);
    FENCE();
    LOAD16_LDS(gB[2], B0 + 2 * 8192 + wb);
    LOAD16_LDS(gB[3], B0 + 3 * 8192 + wb);
    FENCE();
    LOAD16_LDS(gA[0], A0 + 0 * 8192 + wb);
    LOAD16_LDS(gA[2], A0 + 2 * 8192 + wb);
    FENCE();
    LOAD16_LDS(gA[1], A0 + 1 * 8192 + wb);
    LOAD16_LDS(gA[3], A0 + 3 * 8192 + wb);
    FENCE();
    LOAD16_LDS(gB[0] + 64, B1 + 0 * 8192 + wb);
    LOAD16_LDS(gB[1] + 64, B1 + 1 * 8192 + wb);
    FENCE();
    LOAD16_LDS(gB[2] + 64, B1 + 2 * 8192 + wb);
    LOAD16_LDS(gB[3] + 64, B1 + 3 * 8192 + wb);
    FENCE();
    LOAD16_LDS(gA[0] + 64, A1 + 0 * 8192 + wb);
    LOAD16_LDS(gA[2] + 64, A1 + 2 * 8192 + wb);
    VMW(6);                                    // tile0 fully resident
    SBAR();
  }

  int kU3 = 64, kU0 = 128, kU1 = 128, kU2 = 128;

  for (int t = 0; t < NT; ++t) {
    char* Ab = smem + (size_t)((t & 1) * 65536);
    char* Bb = Ab + 32768;
    char* An = smem + (size_t)(((t & 1) ^ 1) * 65536);

    // B fragments for the whole tile (read once, held in regs)
    bf16x8 bfr[4][2];
#pragma unroll
    for (int ni = 0; ni < 4; ++ni) {
      bfr[ni][0] = *(const bf16x8*)(Bb + bRow + ni * 2048 + cc0);
      bfr[ni][1] = *(const bf16x8*)(Bb + bRow + ni * 2048 + cc1);
    }

#pragma unroll
    for (int p = 0; p < 4; ++p) {
      bf16x8 af[2][2];
#pragma unroll
      for (int j = 0; j < 2; ++j) {
        af[j][0] = *(const bf16x8*)(Ab + aRow + (2 * p + j) * 2048 + cc0);
        af[j][1] = *(const bf16x8*)(Ab + aRow + (2 * p + j) * 2048 + cc1);
      }
      if (p == 0) {
        if (kU3 < K) {
          LOAD16_LDS(gA[1] + kU3, An + 1 * 8192 + wb);
          LOAD16_LDS(gA[3] + kU3, An + 3 * 8192 + wb);
          kU3 += 64;
        }
      } else if (p == 1) {
        if (kU0 < K) {
          LOAD16_LDS(gB[0] + kU0, Bb + 0 * 8192 + wb);
          LOAD16_LDS(gB[1] + kU0, Bb + 1 * 8192 + wb);
          kU0 += 64;
        }
        if (t <= NT - 3)      { VMW(10); }     // retire u3(t) before p2 reads
        else if (t == NT - 2) { VMW(8);  }     // tail: u0(t+2) not issued
        else                  { VMW(0);  }     // t==NT-1: drain all
      } else if (p == 2) {
        if (kU1 < K) {
          LOAD16_LDS(gB[2] + kU1, Bb + 2 * 8192 + wb);
          LOAD16_LDS(gB[3] + kU1, Bb + 3 * 8192 + wb);
          kU1 += 64;
        }
      } else {
        if (kU2 < K) {
          LOAD16_LDS(gA[0] + kU2, Ab + 0 * 8192 + wb);
          LOAD16_LDS(gA[2] + kU2, Ab + 2 * 8192 + wb);
          kU2 += 64;
        }
        if (t <= NT - 3)      { VMW(8); }      // retire u0,u1,u2(t+1)
        else if (t == NT - 2) { VMW(2); }      // tail
        /* t == NT-1: no wait */
      }
      SBAR();
      LGKM0();
      __builtin_amdgcn_s_setprio(1);
#pragma unroll
      for (int ni = 0; ni < 4; ++ni) {
#pragma unroll
        for (int j = 0; j < 2; ++j) {
          acc[2 * p + j][ni] = MFMA16(af[j][0], bfr[ni][0], acc[2 * p + j][ni]);
          acc[2 * p + j][ni] = MFMA16(af[j][1], bfr[ni][1], acc[2 * p + j][ni]);
        }
      }
      __builtin_amdgcn_s_setprio(0);
      SBAR();
    }
  }

  // ---------------------------------------------------------------- epilogue
  const int rowBase = tileM + wm * 128;
  const int colBase = tileN + wn * 64;
  if (EPI == 0) {
    // bf16 store (+bias) and per-row sum of squares of the ROUNDED values.
    float* sqp = (tileN < 1024) ? sq0 : sq1;
    float bs[4];
#pragma unroll
    for (int ni = 0; ni < 4; ++ni) bs[ni] = bias[colBase + ni * 16 + r16];
#pragma unroll
    for (int mi = 0; mi < 8; ++mi) {
#pragma unroll
      for (int t_ = 0; t_ < 4; ++t_) {
        const int grow = rowBase + mi * 16 + q16 * 4 + t_;
        float ss = 0.f;
#pragma unroll
        for (int ni = 0; ni < 4; ++ni) {
          const int gcol = colBase + ni * 16 + r16;
          const __bf16 bv = (__bf16)(acc[mi][ni][t_] + bs[ni]);
          ((__bf16*)Out)[(size_t)n * sO + (size_t)grow * ldo + gcol] = bv;
          const float f = (float)bv;
          ss += f * f;
        }
        ss += __shfl_xor(ss, 1);
        ss += __shfl_xor(ss, 2);
        ss += __shfl_xor(ss, 4);
        ss += __shfl_xor(ss, 8);
        if (r16 == 0) atomicAdd(&sqp[n * 1024 + grow], ss);
      }
    }
  } else if (EPI == 1) {
    // e = exp(y - 1), y = cosine in [-1,1] -> no max pass needed.
    float cs[4];
#pragma unroll
    for (int ni = 0; ni < 4; ++ni)
      cs[ni] = colS[n * 1024 + colBase + ni * 16 + r16];
#pragma unroll
    for (int mi = 0; mi < 8; ++mi) {
#pragma unroll
      for (int t_ = 0; t_ < 4; ++t_) {
        const int grow = rowBase + mi * 16 + q16 * 4 + t_;
        const float rs = rowS[n * 1024 + grow];
        float ss = 0.f;
#pragma unroll
        for (int ni = 0; ni < 4; ++ni) {
          const int gcol = colBase + ni * 16 + r16;
          const float y = acc[mi][ni][t_] * rsqrtf(fmaxf(rs * cs[ni], 1e-12f));
          const __bf16 e = (__bf16)__expf(y - 1.0f);
          ((__bf16*)Out)[(size_t)n * sO + (size_t)grow * ldo + gcol] = e;
          ss += (float)e;
        }
        ss += __shfl_xor(ss, 1);
        ss += __shfl_xor(ss, 2);
        ss += __shfl_xor(ss, 4);
        ss += __shfl_xor(ss, 8);
        if (r16 == 0) atomicAdd(&sq0[n * 1024 + grow], ss);
      }
    }
  } else {
    float inv[4];
#pragma unroll
    for (int ni = 0; ni < 4; ++ni)
      inv[ni] = 1.0f / colS[n * 1024 + colBase + ni * 16 + r16];
#pragma unroll
    for (int mi = 0; mi < 8; ++mi)
#pragma unroll
      for (int ni = 0; ni < 4; ++ni)
#pragma unroll
        for (int t_ = 0; t_ < 4; ++t_) {
          const int grow = rowBase + mi * 16 + q16 * 4 + t_;
          const int gcol = colBase + ni * 16 + r16;
          ((float*)Out)[(size_t)n * sO + (size_t)grow * ldo + gcol] =
              acc[mi][ni][t_] * inv[ni];
        }
  }
}

// ---------------------------------------------------------------- launch
extern "C" void kernel_launch(void* const* d_in, const int* in_sizes, int n_in,
                              void* d_out, int out_size, void* d_ws, size_t ws_size,
                              hipStream_t stream) {
  const float* X   = (const float*)d_in[0];
  const float* Wk  = (const float*)d_in[1];
  const float* Wq  = (const float*)d_in[2];
  const float* Wk0 = (const float*)d_in[3];
  const float* Wq0 = (const float*)d_in[4];

  char* ws = (char*)d_ws;
  const size_t MB = 1ull << 20;
  // layout (peak ~261 MB, proven in R2): ET aliases Xtb (dead after GEMM1)
  __bf16* Xb   = (__bf16*)(ws);              //  64 MB  [N][C][B]
  __bf16* Xtb  = (__bf16*)(ws + 64 * MB);    //  64 MB  [N][B][C]
  __bf16* ET   = (__bf16*)(ws + 64 * MB);    //  64 MB  alias   [N][Bk][Bq]
  __bf16* Wb   = (__bf16*)(ws + 128 * MB);   //   4 MB  [2C][C]
  __bf16* KQT  = (__bf16*)(ws + 132 * MB);   // 128 MB  [N][B][2C]  (K^T | Q^T)
  float*  DK2  = (float*)(ws + 260 * MB);            // 128 KB
  float*  DQ2  = (float*)(ws + 260 * MB + 128 * 1024);
  float*  S    = (float*)(ws + 260 * MB + 256 * 1024); // ET row sums
  float*  bias2= (float*)(ws + 260 * MB + 384 * 1024);

  const long long M1 = 1024LL * 1024LL;

  // Opt-in for 128 KiB dynamic LDS (cheap host-side calls; unconditional).
  hipFuncSetAttribute(reinterpret_cast<const void*>(&gemm256<0>),
                      hipFuncAttributeMaxDynamicSharedMemorySize, 131072);
  hipFuncSetAttribute(reinterpret_cast<const void*>(&gemm256<1>),
                      hipFuncAttributeMaxDynamicSharedMemorySize, 131072);
  hipFuncSetAttribute(reinterpret_cast<const void*>(&gemm256<2>),
                      hipFuncAttributeMaxDynamicSharedMemorySize, 131072);

  hipMemsetAsync(DK2, 0, 3 * 128 * 1024, stream);  // zero DK2, DQ2, S

  convert_w<<<8192, 256, 0, stream>>>(Wk, Wq, Wk0, Wq0, Wb, bias2);
  convert_x<<<dim3(32, 32, 32), dim3(32, 8), 0, stream>>>(X, Xb, Xtb);

  // GEMM1: KQT[n][b][c2] = sum_d Xtb[n][b][d] * Wb[c2][d] + bias2[c2]
  //        fused: DK2[n][b] = sum K^2, DQ2[n][b] = sum Q^2
  gemm256<0><<<dim3(8, 4, 32), 512, 131072, stream>>>(
      Xtb, Wb, KQT, 1024, 1024, 2048, 1024, M1, 0LL, 2 * M1,
      nullptr, nullptr, bias2, DK2, DQ2);

  // GEMM2: ET[n][k][q] = exp(cos(K_k,Q_q) - 1)  (bf16), S[n][k] = row sums
  gemm256<1><<<dim3(4, 4, 32), 512, 131072, stream>>>(
      KQT, KQT + 1024, ET, 2048, 2048, 1024, 1024, 2 * M1, 2 * M1, M1,
      DK2, DQ2, nullptr, S, nullptr);

  // GEMM3: Z[n][c][j] = (sum_q Xb[n][c][q] * ET[n][j][q]) / S[n][j]
  gemm256<2><<<dim3(4, 4, 32), 512, 131072, stream>>>(
      Xb, ET, (float*)d_out, 1024, 1024, 1024, 1024, M1, M1, M1,
      nullptr, S, nullptr, nullptr, nullptr);
}

// Round 8
// 563.795 us; speedup vs baseline: 1.1689x; 1.0497x over previous
//
#include <hip/hip_runtime.h>

// Problem: N=32, C=1024, B=1024
//   K = Wk@X[n] + Wk0 ; Q = Wq@X[n] + Wq0
//   Y[q,k] = (Q[:,q].K[:,k]) / sqrt(max(|Q_q|^2 |K_k|^2, 1e-12))
//   SM = softmax over q ; Z = X @ SM  -> [N,C,B] fp32
//
// Empirical law from R2-R7: beyond-L2 staging drains at ~12 GB/s/CU no
// matter the locality/pipeline depth (TCP miss-queue issue limit). So THIS
// ROUND halves the cold bytes of GEMM1+GEMM2: X^T, W, KQT all fp8 e4m3,
// mfma_f32_16x16x32_fp8_fp8 (same rate/shape as bf16). Cosine is computed
// on exactly the fp8-rounded K/Q (norms fused on rounded values -> |Y|<=1
// preserved). GEMM3 and Xb stay bf16 (fp8 ET would exceed error budget).
// Proven 4-phase counted-vmcnt schedule, counts halved (VMW(3)); 16B-granule
// XOR swizzle g ^ (r&3) ^ ((r>>2)&3) (2-way-free b64 reads).
//
// NOTE: __launch_bounds__(512) with NO min-wave clause (VGPR cap -> spills
// would corrupt the hand-counted vmcnt pipeline).

typedef __bf16 bf16x8 __attribute__((ext_vector_type(8)));
typedef float  f32x4  __attribute__((ext_vector_type(4)));

#define LOAD16_LDS(g, l)                                                       \
  __builtin_amdgcn_global_load_lds(                                            \
      (const __attribute__((address_space(1))) void*)(g),                      \
      (__attribute__((address_space(3))) void*)(l), 16, 0, 0)

#define FENCE() asm volatile("" ::: "memory")
#define SBAR()                                                                 \
  do { FENCE(); __builtin_amdgcn_s_barrier(); FENCE(); } while (0)
#define LGKM0()                                                                \
  do { asm volatile("s_waitcnt lgkmcnt(0)" ::: "memory");                      \
       __builtin_amdgcn_sched_barrier(0); } while (0)
#define VMW(n)                                                                 \
  do { asm volatile("s_waitcnt vmcnt(" #n ")" ::: "memory");                   \
       __builtin_amdgcn_sched_barrier(0); } while (0)
#define MFMA16(a, b, c) __builtin_amdgcn_mfma_f32_16x16x32_bf16((a), (b), (c), 0, 0, 0)
#define MFMA8(a, b, c)  __builtin_amdgcn_mfma_f32_16x16x32_fp8_fp8((a), (b), (c), 0, 0, 0)

#define F32_TO_FP8PK(a, b) __builtin_amdgcn_cvt_pk_fp8_f32((a), (b), 0, false)
#define FP8_TO_F32(p, s)   __builtin_amdgcn_cvt_f32_fp8((p), (s))

// ---------------------------------------------------------------- converts
__global__ __launch_bounds__(256) void convert_w(
    const float* __restrict__ Wk, const float* __restrict__ Wq,
    const float* __restrict__ Wk0, const float* __restrict__ Wq0,
    unsigned char* __restrict__ W8, float* __restrict__ bias2) {
  int i = blockIdx.x * 256 + threadIdx.x;              // 0 .. 2M-1
  float v = (i < 1048576) ? Wk[i] : Wq[i - 1048576];
  W8[i] = (unsigned char)(F32_TO_FP8PK(v, v) & 0xff);
  if (i < 1024) bias2[i] = Wk0[i];
  if (i >= 1048576 && i < 1048576 + 1024) bias2[1024 + (i - 1048576)] = Wq0[i - 1048576];
}

// Xb bf16 [n][c][b] (for GEMM3) and Xt8 fp8 [n][b][c] (for GEMM1)
__global__ __launch_bounds__(256) void convert_x(
    const float* __restrict__ X, __bf16* __restrict__ Xb,
    unsigned char* __restrict__ Xt8) {
  const int n = blockIdx.z;
  const int c0 = blockIdx.y * 32, b0 = blockIdx.x * 32;
  __shared__ float t[32][33];
  const int tx = threadIdx.x, ty = threadIdx.y;        // 32 x 8
  const float* Xn = X + (size_t)n * 1024 * 1024;
  __bf16* Xbn = Xb + (size_t)n * 1024 * 1024;
  unsigned char* Xtn = Xt8 + (size_t)n * 1024 * 1024;
#pragma unroll
  for (int i = 0; i < 4; ++i) {
    int c = c0 + ty + i * 8;
    float v = Xn[(size_t)c * 1024 + b0 + tx];
    Xbn[(size_t)c * 1024 + b0 + tx] = (__bf16)v;
    t[ty + i * 8][tx] = v;
  }
  __syncthreads();
#pragma unroll
  for (int i = 0; i < 4; ++i) {
    int b = b0 + ty + i * 8;
    float v = t[tx][ty + i * 8];
    Xtn[(size_t)b * 1024 + c0 + tx] = (unsigned char)(F32_TO_FP8PK(v, v) & 0xff);
  }
}

// ---------------------------------------------------------------- fp8 NT GEMM
// C[m,n'] = sum_k A[m,k]*B[n',k]; fp8 e4m3 rows k-contiguous (lda/ldb BYTES).
// 256x256 tile, BK=64 (bytes=elems), 8 waves (2Mx4N), per-wave C = 128x64.
// LDS/buffer: A[256][64B]=16K + B 16K; 2 buffers = 64 KB.
// Row = 64B = 4 granules of 16B; granule g stored at g ^ (r&3) ^ ((r>>2)&3).
// Staging call = 8KB: wave w covers chunk-half h=w>>2, rows (w&3)*16+(lane>>2)
// of a 64-row chunk; per-lane 16B at pre-swizzled source granule (lane-only
// swizzle: (lane&3)^((lane>>2)&3)^((lane>>4)&3)).
// Units/tile (1 call each): u0=Bchunks01, u1=B23, u2=Achunks0&2, u3=A1&3.
// Schedule (mirrors the proven bf16 one, counts halved):
//   p0: bfr(all)+af(0,1), issue u3(t+1) | p1: af(2,3), issue u0(t+2)
//   p2: af(4,5), issue u1(t+2)          | p3: af(6,7), issue u2(t+2),
//       VMW(3) (t<NT-2) else VMW(0)
//   each phase: SBAR; lgkmcnt(0); setprio(1); 16 MFMA; setprio(0); SBAR
// EPI 0: fp8 out (+bias[col]); per-row sum-of-squares of ROUNDED -> atomicAdd
// EPI 1: e = exp(v*rsqrt(max(rowS*colS,eps)) - 1) bf16 out; row-sum -> sq0
template <int EPI>
__global__ __launch_bounds__(512) void gemm_fp8(
    const unsigned char* __restrict__ A, const unsigned char* __restrict__ Bm,
    void* __restrict__ Out, int lda, int ldb, int ldo, int K,
    long long sA, long long sB, long long sO,
    const float* __restrict__ rowS, const float* __restrict__ colS,
    const float* __restrict__ bias,
    float* __restrict__ sq0, float* __restrict__ sq1) {
  extern __shared__ char smem[];
  const int n = blockIdx.z;
  A += (size_t)n * sA;
  Bm += (size_t)n * sB;
  const int tileM = blockIdx.y * 256, tileN = blockIdx.x * 256;

  const int tid = threadIdx.x, w = tid >> 6, lane = tid & 63;
  const int wm = w >> 2, wn = w & 3;
  const int r16 = lane & 15, q16 = lane >> 4;

  // ---- staging addressing
  const int hf = w >> 2, wq = w & 3;
  const int srow = wq * 16 + (lane >> 2);                  // 0..63 within chunk
  const int scol = (((lane & 3) ^ ((lane >> 2) & 3) ^ ((lane >> 4) & 3)) << 4);
  const unsigned char* gA2 = A + (size_t)(tileM + hf * 128 + srow) * lda + scol;
  const unsigned char* gA3 = A + (size_t)(tileM + 64 + hf * 128 + srow) * lda + scol;
  const unsigned char* gB0 = Bm + (size_t)(tileN + hf * 64 + srow) * ldb + scol;
  const unsigned char* gB1 = Bm + (size_t)(tileN + 128 + hf * 64 + srow) * ldb + scol;
  const int dA2 = hf * 8192 + wq * 1024;                   // A chunks 0,2
  const int dA3 = dA2 + 4096;                              // A chunks 1,3
  const int dB0 = hf * 4096 + wq * 1024;                   // B chunks 0,1
  const int dB1 = dB0 + 8192;                              // B chunks 2,3

  // ---- fragment reads (b64): row r16, k-half h, quad q16
  const int s16 = (r16 & 3) ^ ((r16 >> 2) & 3);
  const int cc0 = (((q16 >> 1) ^ s16) << 4) + ((q16 & 1) << 3);
  const int cc1 = cc0 ^ 32;
  const int aRow = (wm * 128 + r16) * 64;                  // + mi*1024
  const int bRow = (wn * 64 + r16) * 64;                   // + ni*1024

  f32x4 acc[8][4];
#pragma unroll
  for (int i = 0; i < 8; ++i)
#pragma unroll
    for (int j = 0; j < 4; ++j) acc[i][j] = (f32x4){0.f, 0.f, 0.f, 0.f};

  const int NT = K >> 6;

  // ---- prologue: tile0 u0..u3 + tile1 u0..u2
  {
    char* A0 = smem;
    char* B0 = smem + 16384;
    char* A1 = smem + 32768;
    char* B1 = A1 + 16384;
    LOAD16_LDS(gB0, B0 + dB0); FENCE();
    LOAD16_LDS(gB1, B0 + dB1); FENCE();
    LOAD16_LDS(gA2, A0 + dA2); FENCE();
    LOAD16_LDS(gA3, A0 + dA3); FENCE();
    LOAD16_LDS(gB0 + 64, B1 + dB0); FENCE();
    LOAD16_LDS(gB1 + 64, B1 + dB1); FENCE();
    LOAD16_LDS(gA2 + 64, A1 + dA2);
    VMW(3);                                   // tile0 fully resident
    SBAR();
  }

  int kU3 = 64, kU0 = 128, kU1 = 128, kU2 = 128;

  for (int t = 0; t < NT; ++t) {
    char* Ab = smem + (size_t)((t & 1) * 32768);
    char* Bb = Ab + 16384;
    char* An = smem + (size_t)(((t & 1) ^ 1) * 32768);

    long bfr[4][2];
#pragma unroll
    for (int ni = 0; ni < 4; ++ni) {
      bfr[ni][0] = *(const long*)(Bb + bRow + ni * 1024 + cc0);
      bfr[ni][1] = *(const long*)(Bb + bRow + ni * 1024 + cc1);
    }

#pragma unroll
    for (int p = 0; p < 4; ++p) {
      long af[2][2];
#pragma unroll
      for (int j = 0; j < 2; ++j) {
        af[j][0] = *(const long*)(Ab + aRow + (2 * p + j) * 1024 + cc0);
        af[j][1] = *(const long*)(Ab + aRow + (2 * p + j) * 1024 + cc1);
      }
      if (p == 0) {
        if (kU3 < K) { LOAD16_LDS(gA3 + kU3, An + dA3); kU3 += 64; }
      } else if (p == 1) {
        if (kU0 < K) { LOAD16_LDS(gB0 + kU0, Bb + dB0); kU0 += 64; }
      } else if (p == 2) {
        if (kU1 < K) { LOAD16_LDS(gB1 + kU1, Bb + dB1); kU1 += 64; }
      } else {
        if (kU2 < K) { LOAD16_LDS(gA2 + kU2, Ab + dA2); kU2 += 64; }
        if (t < NT - 2) { VMW(3); } else { VMW(0); }
      }
      SBAR();
      LGKM0();
      __builtin_amdgcn_s_setprio(1);
#pragma unroll
      for (int ni = 0; ni < 4; ++ni) {
#pragma unroll
        for (int j = 0; j < 2; ++j) {
          acc[2 * p + j][ni] = MFMA8(af[j][0], bfr[ni][0], acc[2 * p + j][ni]);
          acc[2 * p + j][ni] = MFMA8(af[j][1], bfr[ni][1], acc[2 * p + j][ni]);
        }
      }
      __builtin_amdgcn_s_setprio(0);
      SBAR();
    }
  }

  // ---------------------------------------------------------------- epilogue
  const int rowBase = tileM + wm * 128;
  const int colBase = tileN + wn * 64;
  if (EPI == 0) {
    float* sqp = (tileN < 1024) ? sq0 : sq1;
    float bs[4];
#pragma unroll
    for (int ni = 0; ni < 4; ++ni) bs[ni] = bias[colBase + ni * 16 + r16];
#pragma unroll
    for (int mi = 0; mi < 8; ++mi) {
#pragma unroll
      for (int t_ = 0; t_ < 4; ++t_) {
        const int grow = rowBase + mi * 16 + q16 * 4 + t_;
        const int p01 = F32_TO_FP8PK(acc[mi][0][t_] + bs[0], acc[mi][1][t_] + bs[1]);
        const int p23 = F32_TO_FP8PK(acc[mi][2][t_] + bs[2], acc[mi][3][t_] + bs[3]);
        unsigned char* orow = (unsigned char*)Out + (size_t)n * sO + (size_t)grow * ldo;
        orow[colBase + 0 * 16 + r16] = (unsigned char)(p01 & 0xff);
        orow[colBase + 1 * 16 + r16] = (unsigned char)((p01 >> 8) & 0xff);
        orow[colBase + 2 * 16 + r16] = (unsigned char)(p23 & 0xff);
        orow[colBase + 3 * 16 + r16] = (unsigned char)((p23 >> 8) & 0xff);
        const float f0 = FP8_TO_F32(p01, 0), f1 = FP8_TO_F32(p01, 1);
        const float f2 = FP8_TO_F32(p23, 0), f3 = FP8_TO_F32(p23, 1);
        float ss = f0 * f0 + f1 * f1 + f2 * f2 + f3 * f3;
        ss += __shfl_xor(ss, 1);
        ss += __shfl_xor(ss, 2);
        ss += __shfl_xor(ss, 4);
        ss += __shfl_xor(ss, 8);
        if (r16 == 0) atomicAdd(&sqp[n * 1024 + grow], ss);
      }
    }
  } else {
    // e = exp(y - 1), y = exact cosine of the fp8-rounded vectors, |y|<=1.
    float cs[4];
#pragma unroll
    for (int ni = 0; ni < 4; ++ni)
      cs[ni] = colS[n * 1024 + colBase + ni * 16 + r16];
#pragma unroll
    for (int mi = 0; mi < 8; ++mi) {
#pragma unroll
      for (int t_ = 0; t_ < 4; ++t_) {
        const int grow = rowBase + mi * 16 + q16 * 4 + t_;
        const float rs = rowS[n * 1024 + grow];
        float ss = 0.f;
#pragma unroll
        for (int ni = 0; ni < 4; ++ni) {
          const int gcol = colBase + ni * 16 + r16;
          const float y = acc[mi][ni][t_] * rsqrtf(fmaxf(rs * cs[ni], 1e-12f));
          const __bf16 e = (__bf16)__expf(y - 1.0f);
          ((__bf16*)Out)[(size_t)n * sO + (size_t)grow * ldo + gcol] = e;
          ss += (float)e;
        }
        ss += __shfl_xor(ss, 1);
        ss += __shfl_xor(ss, 2);
        ss += __shfl_xor(ss, 4);
        ss += __shfl_xor(ss, 8);
        if (r16 == 0) atomicAdd(&sq0[n * 1024 + grow], ss);
      }
    }
  }
}

// ---------------------------------------------------------------- bf16 NT GEMM (GEMM3)
// Unchanged from the proven R2 kernel; EPI2 only: f32 out * (1/colS[col]).
__global__ __launch_bounds__(512) void gemm256(
    const __bf16* __restrict__ A, const __bf16* __restrict__ Bm,
    float* __restrict__ Out, int lda, int ldb, int ldo, int K,
    long long sA, long long sB, long long sO,
    const float* __restrict__ colS) {
  extern __shared__ char smem[];
  const int n = blockIdx.z;
  A += (size_t)n * sA;
  Bm += (size_t)n * sB;
  const int tileM = blockIdx.y * 256, tileN = blockIdx.x * 256;

  const int tid = threadIdx.x, w = tid >> 6, lane = tid & 63;
  const int wm = w >> 2, wn = w & 3;
  const int r16 = lane & 15, q16 = lane >> 4;
  const int wb = w * 1024;

  const int srow = tid >> 3;
  const int scol8 = ((tid & 7) ^ (srow & 7)) * 8;
  const __bf16* gA[4];
  const __bf16* gB[4];
#pragma unroll
  for (int c = 0; c < 4; ++c) {
    gA[c] = A + (size_t)(tileM + c * 64 + srow) * lda + scol8;
    gB[c] = Bm + (size_t)(tileN + c * 64 + srow) * ldb + scol8;
  }

  const int sw = (r16 & 7) << 4;
  const int cc0 = (q16 * 16) ^ sw;
  const int cc1 = cc0 ^ 64;
  const int aRow = (wm * 128 + r16) * 128;
  const int bRow = (wn * 64 + r16) * 128;

  f32x4 acc[8][4];
#pragma unroll
  for (int i = 0; i < 8; ++i)
#pragma unroll
    for (int j = 0; j < 4; ++j) acc[i][j] = (f32x4){0.f, 0.f, 0.f, 0.f};

  const int NT = K >> 6;

  {
    char* A0 = smem;
    char* B0 = smem + 32768;
    char* A1 = smem + 65536;
    char* B1 = smem + 65536 + 32768;
    LOAD16_LDS(gB[0], B0 + 0 * 8192 + wb);
    LOAD16_LDS(gB[1], B0 + 1 * 8192 + wb);
    FENCE();
    LOAD16_LDS(gB[2], B0 + 2 * 8192 + wb);
    LOAD16_LDS(gB[3], B0 + 3 * 8192 + wb);
    FENCE();
    LOAD16_LDS(gA[0], A0 + 0 * 8192 + wb);
    LOAD16_LDS(gA[2], A0 + 2 * 8192 + wb);
    FENCE();
    LOAD16_LDS(gA[1], A0 + 1 * 8192 + wb);
    LOAD16_LDS(gA[3], A0 + 3 * 8192 + wb);
    FENCE();
    LOAD16_LDS(gB[0] + 64, B1 + 0 * 8192 + wb);
    LOAD16_LDS(gB[1] + 64, B1 + 1 * 8192 + wb);
    FENCE();
    LOAD16_LDS(gB[2] + 64, B1 + 2 * 8192 + wb);
    LOAD16_LDS(gB[3] + 64, B1 + 3 * 8192 + wb);
    FENCE();
    LOAD16_LDS(gA[0] + 64, A1 + 0 * 8192 + wb);
    LOAD16_LDS(gA[2] + 64, A1 + 2 * 8192 + wb);
    VMW(6);
    SBAR();
  }

  int kU3 = 64, kU0 = 128, kU1 = 128, kU2 = 128;

  for (int t = 0; t < NT; ++t) {
    char* Ab = smem + (size_t)((t & 1) * 65536);
    char* Bb = Ab + 32768;
    char* An = smem + (size_t)(((t & 1) ^ 1) * 65536);

    bf16x8 bfr[4][2];
#pragma unroll
    for (int ni = 0; ni < 4; ++ni) {
      bfr[ni][0] = *(const bf16x8*)(Bb + bRow + ni * 2048 + cc0);
      bfr[ni][1] = *(const bf16x8*)(Bb + bRow + ni * 2048 + cc1);
    }

#pragma unroll
    for (int p = 0; p < 4; ++p) {
      bf16x8 af[2][2];
#pragma unroll
      for (int j = 0; j < 2; ++j) {
        af[j][0] = *(const bf16x8*)(Ab + aRow + (2 * p + j) * 2048 + cc0);
        af[j][1] = *(const bf16x8*)(Ab + aRow + (2 * p + j) * 2048 + cc1);
      }
      if (p == 0) {
        if (kU3 < K) {
          LOAD16_LDS(gA[1] + kU3, An + 1 * 8192 + wb);
          LOAD16_LDS(gA[3] + kU3, An + 3 * 8192 + wb);
          kU3 += 64;
        }
      } else if (p == 1) {
        if (kU0 < K) {
          LOAD16_LDS(gB[0] + kU0, Bb + 0 * 8192 + wb);
          LOAD16_LDS(gB[1] + kU0, Bb + 1 * 8192 + wb);
          kU0 += 64;
        }
      } else if (p == 2) {
        if (kU1 < K) {
          LOAD16_LDS(gB[2] + kU1, Bb + 2 * 8192 + wb);
          LOAD16_LDS(gB[3] + kU1, Bb + 3 * 8192 + wb);
          kU1 += 64;
        }
      } else {
        if (kU2 < K) {
          LOAD16_LDS(gA[0] + kU2, Ab + 0 * 8192 + wb);
          LOAD16_LDS(gA[2] + kU2, Ab + 2 * 8192 + wb);
          kU2 += 64;
        }
        if (t < NT - 2) { VMW(6); } else { VMW(0); }
      }
      SBAR();
      LGKM0();
      __builtin_amdgcn_s_setprio(1);
#pragma unroll
      for (int ni = 0; ni < 4; ++ni) {
#pragma unroll
        for (int j = 0; j < 2; ++j) {
          acc[2 * p + j][ni] = MFMA16(af[j][0], bfr[ni][0], acc[2 * p + j][ni]);
          acc[2 * p + j][ni] = MFMA16(af[j][1], bfr[ni][1], acc[2 * p + j][ni]);
        }
      }
      __builtin_amdgcn_s_setprio(0);
      SBAR();
    }
  }

  const int rowBase = tileM + wm * 128;
  const int colBase = tileN + wn * 64;
  float inv[4];
#pragma unroll
  for (int ni = 0; ni < 4; ++ni)
    inv[ni] = 1.0f / colS[n * 1024 + colBase + ni * 16 + r16];
#pragma unroll
  for (int mi = 0; mi < 8; ++mi)
#pragma unroll
    for (int ni = 0; ni < 4; ++ni)
#pragma unroll
      for (int t_ = 0; t_ < 4; ++t_) {
        const int grow = rowBase + mi * 16 + q16 * 4 + t_;
        const int gcol = colBase + ni * 16 + r16;
        Out[(size_t)n * sO + (size_t)grow * ldo + gcol] = acc[mi][ni][t_] * inv[ni];
      }
}

// ---------------------------------------------------------------- launch
extern "C" void kernel_launch(void* const* d_in, const int* in_sizes, int n_in,
                              void* d_out, int out_size, void* d_ws, size_t ws_size,
                              hipStream_t stream) {
  const float* X   = (const float*)d_in[0];
  const float* Wk  = (const float*)d_in[1];
  const float* Wq  = (const float*)d_in[2];
  const float* Wk0 = (const float*)d_in[3];
  const float* Wq0 = (const float*)d_in[4];

  char* ws = (char*)d_ws;
  const size_t MB = 1ull << 20;
  // layout, peak ~226.5 MB (< proven 273 MB bound):
  __bf16*        Xb   = (__bf16*)(ws);                  //  64 MB [N][C][B] bf16
  unsigned char* Xt8  = (unsigned char*)(ws + 64 * MB); //  32 MB [N][B][C] fp8
  __bf16*        ET   = (__bf16*)(ws + 96 * MB);        //  64 MB [N][Bk][Bq] bf16
  unsigned char* W8   = (unsigned char*)(ws + 160 * MB);//   2 MB [2C][C] fp8
  unsigned char* KQT8 = (unsigned char*)(ws + 162 * MB);//  64 MB [N][B][2C] fp8
  float*  DK2  = (float*)(ws + 226 * MB);               // 128 KB
  float*  DQ2  = (float*)(ws + 226 * MB + 128 * 1024);
  float*  S    = (float*)(ws + 226 * MB + 256 * 1024);
  float*  bias2= (float*)(ws + 226 * MB + 384 * 1024);

  const long long M1 = 1024LL * 1024LL;

  hipFuncSetAttribute(reinterpret_cast<const void*>(&gemm_fp8<0>),
                      hipFuncAttributeMaxDynamicSharedMemorySize, 65536);
  hipFuncSetAttribute(reinterpret_cast<const void*>(&gemm_fp8<1>),
                      hipFuncAttributeMaxDynamicSharedMemorySize, 65536);
  hipFuncSetAttribute(reinterpret_cast<const void*>(&gemm256),
                      hipFuncAttributeMaxDynamicSharedMemorySize, 131072);

  hipMemsetAsync(DK2, 0, 3 * 128 * 1024, stream);  // zero DK2, DQ2, S

  convert_w<<<8192, 256, 0, stream>>>(Wk, Wq, Wk0, Wq0, W8, bias2);
  convert_x<<<dim3(32, 32, 32), dim3(32, 8), 0, stream>>>(X, Xb, Xt8);

  // GEMM1 (fp8): KQT8[n][b][c2] = fp8( sum_d Xt8[n][b][d]*W8[c2][d] + bias2 )
  //              fused: DK2/DQ2 = per-row sums of squares of the fp8 values
  gemm_fp8<0><<<dim3(8, 4, 32), 512, 65536, stream>>>(
      Xt8, W8, KQT8, 1024, 1024, 2048, 1024, M1, 0LL, 2 * M1,
      nullptr, nullptr, bias2, DK2, DQ2);

  // GEMM2 (fp8): ET[n][k][q] = exp(cos(K_k,Q_q) - 1) bf16, S[n][k] row sums
  gemm_fp8<1><<<dim3(4, 4, 32), 512, 65536, stream>>>(
      KQT8, KQT8 + 1024, ET, 2048, 2048, 1024, 1024, 2 * M1, 2 * M1, M1,
      DK2, DQ2, nullptr, S, nullptr);

  // GEMM3 (bf16): Z[n][c][j] = (sum_q Xb[n][c][q] * ET[n][j][q]) / S[n][j]
  gemm256<<<dim3(4, 4, 32), 512, 131072, stream>>>(
      Xb, ET, (float*)d_out, 1024, 1024, 1024, 1024, M1, M1, M1, S);
}